// Round 2
// baseline (1502.712 us; speedup 1.0000x reference)
//
#include <hip/hip_runtime.h>
#include <stdint.h>
#include <stddef.h>

#define VOCAB 41
#define EMB   512
#define HID   1024
#define H3    3072
#define BB    128
#define TT    256
#define BT    (BB*TT)
#define NSLOT 4
#define SLOT_U32 (8*32*512)    // 131072 dwords = 512 KB per slot

typedef unsigned short u16;
typedef uint32_t u32;
typedef _Float16 half_t;
typedef half_t f16x8 __attribute__((ext_vector_type(8)));
typedef float f32x4 __attribute__((ext_vector_type(4)));
typedef u32 u32x4 __attribute__((ext_vector_type(4)));

__device__ __forceinline__ float bf2f(u16 u) {
  return __uint_as_float(((uint32_t)u) << 16);
}
__device__ __forceinline__ u16 f2bf(float f) {
  uint32_t x = __float_as_uint(f);
  return (u16)((x + 0x7FFFu + ((x >> 16) & 1u)) >> 16);
}
__device__ __forceinline__ u16 f2h_bits(float f) {
  half_t h = (half_t)f;
  return __builtin_bit_cast(u16, h);
}
__device__ __forceinline__ float sigmoidf_(float x) {
  return 1.0f / (1.0f + __expf(-x));
}
__device__ __forceinline__ float tanh_fast(float x) {
  return 1.0f - 2.0f / (__expf(2.0f * x) + 1.0f);
}

// ---------- prologue kernels ----------

__global__ void detect_kernel(const u16* __restrict__ raw, int* __restrict__ flag) {
  __shared__ int s[256];
  int tid = threadIdx.x, cnt = 0;
  for (int i = tid; i < 4096; i += 256) {
    int e = (raw[i] >> 7) & 0xFF;
    if (e >= 132) cnt++;
  }
  s[tid] = cnt; __syncthreads();
  if (tid == 0) {
    int tot = 0;
    for (int i = 0; i < 256; i++) tot += s[i];
    *flag = (tot > 4) ? 1 : 0;
  }
}

__global__ void conv_kernel(const void* __restrict__ src, float* __restrict__ dst,
                            int n, const int* __restrict__ flag) {
  int i = blockIdx.x * 256 + threadIdx.x;
  if (i >= n) return;
  if (*flag) dst[i] = ((const float*)src)[i];
  else       dst[i] = bf2f(((const u16*)src)[i]);
}

__global__ void tokm_kernel(const int* __restrict__ x,
                            const unsigned char* __restrict__ m,
                            int* __restrict__ tokm) {
  int i = blockIdx.x * 256 + threadIdx.x;
  unsigned char b0 = m[0], b1 = m[1];
  bool t;
  if (b0 == 1) {
    if (b1 != 0) t = (m[i] != 0);
    else         t = (((const int*)m)[i] != 0);
  } else if (b0 == 0x80) {
    t = (((const u16*)m)[i] != 0);
  } else {
    t = (((const float*)m)[i] != 0.0f);
  }
  tokm[i] = x[i] | (t ? 0 : 0x80000000);
}

__global__ __launch_bounds__(256) void proj_kernel(
    const void* __restrict__ emb, const void* __restrict__ gk,
    const float* __restrict__ gbf, float* __restrict__ P,
    const int* __restrict__ flag) {
  int v = blockIdx.x / (H3 / 256);
  int j = (blockIdx.x % (H3 / 256)) * 256 + threadIdx.x;
  float acc = gbf[j];
  if (*flag) {
    const float* e = (const float*)emb + v * EMB;
    const float* g = (const float*)gk;
    for (int k = 0; k < EMB; ++k) acc = fmaf(e[k], g[k * H3 + j], acc);
  } else {
    const u16* e = (const u16*)emb + v * EMB;
    const u16* g = (const u16*)gk;
    for (int k = 0; k < EMB; ++k) acc = fmaf(bf2f(e[k]), bf2f(g[k * H3 + j]), acc);
  }
  P[v * H3 + j] = acc;
}

__global__ void p2_kernel(const float* __restrict__ P, const float* __restrict__ gbf,
                          float* __restrict__ P2) {
  int gc = blockIdx.x;
  int v = threadIdx.x;
  if (v >= VOCAB) return;
  float val = P[v * H3 + gc];
  if (gc < 2048) val += gbf[H3 + gc];
  P2[gc * VOCAB + v] = val;
}

// Fat-block Wimg: [ds 0..31][ks 0..31][c 0..5][lane][j], c = g*2 + dh,
// col = g*1024 + ds*32 + dh*16 + (lane&15), k = ks*32 + (lane>>4)*8 + j.
__global__ void pack_wimg_kernel(const void* __restrict__ src, u16* __restrict__ img,
                                 const int* __restrict__ flag) {
  int idx = blockIdx.x * 256 + threadIdx.x;       // 0 .. 3,145,727
  int j = idx & 7;
  int t1 = idx >> 3;
  int lane = t1 & 63;
  int t2 = t1 >> 6;
  int c = t2 % 6;
  int t3 = t2 / 6;
  int ks = t3 & 31;
  int ds = t3 >> 5;
  int g = c >> 1, dh = c & 1;
  int k = ks * 32 + (lane >> 4) * 8 + j;
  int col = g * 1024 + ds * 32 + dh * 16 + (lane & 15);
  float val;
  if (*flag) val = ((const float*)src)[(size_t)k * H3 + col];
  else       val = bf2f(((const u16*)src)[(size_t)k * H3 + col]);
  img[idx] = f2h_bits(val);
}

__global__ void pack_dimg_kernel(const void* __restrict__ src, u16* __restrict__ img,
                                 const int* __restrict__ flag) {
  int idx = blockIdx.x * 256 + threadIdx.x;
  int j = idx & 7;
  int t1 = idx >> 3;
  int lane = t1 & 63;
  int t2 = t1 >> 6;
  int ct = t2 % 3;
  int ks = t2 / 3;
  int k = ks * 32 + (lane >> 4) * 8 + j;
  int v = ct * 16 + (lane & 15);
  float val = 0.0f;
  if (v < VOCAB) {
    if (*flag) val = ((const float*)src)[(size_t)k * VOCAB + v];
    else       val = bf2f(((const u16*)src)[(size_t)k * VOCAB + v]);
  }
  img[idx] = f2h_bits(val);
}

// ---------- persistent GRU: tagged exchange, two-tier coherence ---------
// 256 blocks x 256 thr (1/CU). bid = ds*8 + gt. Block: 16 rows (gt) x 32
// dims (ds), K split across 4 waves; 6 acc tiles/wave.
//
// KEY: gt = bid & 7 == dispatch XCD (round-robin bid%8), so all 32 blocks
// of a gt group share ONE XCD L2. Exchange therefore goes through the
// shared L2 (fast path), with a MALL write-through safety net:
//   Producer: plain store (updates shared L2, dirty)  +  sc1 store
//             (write-through; never awaited, background safety copy).
//   Consumer: sc0 loads (bypass L1, hit shared L2). A wave that spins
//             >1024 tries STICKILY escalates to sc0+sc1 bypass loads that
//             read the written-through copy -- correctness never depends
//             on the placement heuristic, only speed does.
// Payload stays self-validating: each dword = (step_tag<<16)|f16, dword
// single-copy atomicity => tag match guarantees same-step data; no flags,
// no drains, stale/partial arrivals just retry.
// Slot reuse (NSLOT=4): a block posting tag t+1 has consumed tags t =>
// all same-gt blocks posted >= t => all consumed <= t-1 => overwriting
// t-3 data is safe; tags disambiguate mod-4 reuse exactly.
__global__ __launch_bounds__(256, 1) void gru_persist(
    const uint4* __restrict__ Wimg, const int* __restrict__ tokm,
    const float* __restrict__ P2, const float* __restrict__ gbf,
    u32* __restrict__ exch, u16* __restrict__ Hout) {
  int bid = blockIdx.x;
  int gt = bid & 7, ds = bid >> 3;     // ds 0..31
  int tid = threadIdx.x;
  int w = tid >> 6, lane = tid & 63;

  __shared__ float red[4][64][25];     // 24 acc floats/lane, pad 25
  __shared__ __align__(16) u16 tr[512];   // 16 rows x 32 dims
  __shared__ float Pl[3][32][41];
  __shared__ int tokL[16 * 259];

  // persistent B fragments: 6 tiles x 8 k-steps (this wave's K-quarter)
  f16x8 breg[6][8];
  {
    const uint4* wsrc = Wimg + (size_t)ds * (32 * 6) * 64 + lane;
    #pragma unroll
    for (int k8 = 0; k8 < 8; ++k8)
      #pragma unroll
      for (int c = 0; c < 6; ++c)
        breg[c][k8] = __builtin_bit_cast(f16x8, wsrc[((w * 8 + k8) * 6 + c) * 64]);
  }

  // preload epilogue tables: P2 slice (3x32x41) and token map (16x256)
  for (int i = tid; i < 3 * 32 * VOCAB; i += 256) {
    int v = i % VOCAB;
    int t1 = i / VOCAB;
    int di = t1 & 31, g = t1 >> 5;
    Pl[g][di][v] = P2[(size_t)(g * 1024 + ds * 32 + di) * VOCAB + v];
  }
  for (int i = tid; i < 16 * 256; i += 256) {
    int rr = i >> 8, cc = i & 255;
    tokL[rr * 259 + cc] = tokm[gt * 4096 + i];
  }

  // per-thread epilogue ownership: (row, dimb) and (row, dimb+16)
  int row = tid >> 4, dimb = tid & 15;
  int lane_src = (row >> 2) * 16 + dimb;
  int rg = row & 3;
  float b1h0 = gbf[H3 + 2048 + ds * 32 + dimb];
  float b1h1 = gbf[H3 + 2048 + ds * 32 + dimb + 16];
  float hc0 = 0.f, hc1 = 0.f;
  __syncthreads();                     // protect LDS preloads

  int coh = 0;                         // sticky: 0 = L2 fast path, 1 = bypass
  u32x4 d[16];                         // bulk tagged A data (this wave's K-quarter)
  for (int t = 0; t < TT; ++t) {
    const u32* slotb = exch + (size_t)(t & (NSLOT - 1)) * SLOT_U32;
    const u32* abase = slotb + (size_t)(gt * 32 + w * 8) * 512 + lane * 8;
    // 64-lane sentinel net: 8 producers x 8 sample dwords {0,73,...,511}
    // (producer lanes 0,9,18,...,63) -> partial arrivals rarely reach verify
    const u32* sp = slotb + (size_t)(gt * 32 + w * 8 + (lane >> 3)) * 512 +
                    (lane & 7) * 73;
    u32 want = ((u32)t) << 16;
    int tries = 0;
    while (true) {
      u32 v;
      if (!coh)
        asm volatile("global_load_dword %0, %1, off sc0\n\ts_waitcnt vmcnt(0)"
                     : "=v"(v) : "v"(sp) : "memory");
      else
        asm volatile("global_load_dword %0, %1, off sc0 sc1\n\ts_waitcnt vmcnt(0)"
                     : "=v"(v) : "v"(sp) : "memory");
      __builtin_amdgcn_sched_barrier(0);
      if (__ballot((v & 0xFFFF0000u) != want) == 0ULL) {
        // bulk load + full per-dword tag verify
        if (!coh) {
          #pragma unroll
          for (int i = 0; i < 8; ++i)
            asm volatile("global_load_dwordx4 %0, %2, off sc0\n\t"
                         "global_load_dwordx4 %1, %2, off offset:16 sc0"
                         : "=&v"(d[2 * i]), "=&v"(d[2 * i + 1])
                         : "v"(abase + (size_t)i * 512) : "memory");
        } else {
          #pragma unroll
          for (int i = 0; i < 8; ++i)
            asm volatile("global_load_dwordx4 %0, %2, off sc0 sc1\n\t"
                         "global_load_dwordx4 %1, %2, off offset:16 sc0 sc1"
                         : "=&v"(d[2 * i]), "=&v"(d[2 * i + 1])
                         : "v"(abase + (size_t)i * 512) : "memory");
        }
        asm volatile("s_waitcnt vmcnt(0)" ::: "memory");
        __builtin_amdgcn_sched_barrier(0);
        u32 bad = 0;
        #pragma unroll
        for (int i = 0; i < 16; ++i) {
          u32x4 q = d[i];
          bad |= (q.x ^ want) | (q.y ^ want) | (q.z ^ want) | (q.w ^ want);
        }
        bad &= 0xFFFF0000u;
        if (__ballot(bad != 0) == 0ULL) break;
      }
      __builtin_amdgcn_s_sleep(1);
      if (++tries > 1024) coh = 1;     // sticky escalation (placement-proof)
      if (tries > (1 << 17)) break;    // fail fast instead of hanging
    }

    // --- pack low halves -> f16x8 fragments, MFMA ---
    f32x4 acc[6];
    #pragma unroll
    for (int c = 0; c < 6; ++c) acc[c] = (f32x4){0.f, 0.f, 0.f, 0.f};
    #pragma unroll
    for (int k8 = 0; k8 < 8; ++k8) {
      u32x4 lo = d[2 * k8], hi = d[2 * k8 + 1];
      u32x4 pk;
      pk.x = (lo.y << 16) | (lo.x & 0xFFFFu);
      pk.y = (lo.w << 16) | (lo.z & 0xFFFFu);
      pk.z = (hi.y << 16) | (hi.x & 0xFFFFu);
      pk.w = (hi.w << 16) | (hi.z & 0xFFFFu);
      f16x8 a = __builtin_bit_cast(f16x8, pk);
      #pragma unroll
      for (int c = 0; c < 6; ++c)
        acc[c] = __builtin_amdgcn_mfma_f32_16x16x32_f16(a, breg[c][k8], acc[c], 0, 0, 0);
    }

    {
      float* q = red[w][lane];
      #pragma unroll
      for (int c = 0; c < 6; ++c)
        #pragma unroll
        for (int r = 0; r < 4; ++r) q[c * 4 + r] = acc[c][r];
    }
    __syncthreads();                                   // S2

    // per-thread reduce over 4 K-quarters + gate epilogue (2 dims)
    {
      int tm = tokL[row * 259 + t];
      int tok = tm & 0xFFFF;
      #pragma unroll
      for (int dh = 0; dh < 2; ++dh) {
        float a0 = 0.f, a1 = 0.f, a2 = 0.f;
        #pragma unroll
        for (int ww = 0; ww < 4; ++ww) {
          const float* q = red[ww][lane_src];
          a0 += q[(0 * 2 + dh) * 4 + rg];
          a1 += q[(1 * 2 + dh) * 4 + rg];
          a2 += q[(2 * 2 + dh) * 4 + rg];
        }
        int dglob = dimb + dh * 16;
        float z  = sigmoidf_(Pl[0][dglob][tok] + a0);
        float r_ = sigmoidf_(Pl[1][dglob][tok] + a1);
        float b1h = dh ? b1h1 : b1h0;
        float hh = tanh_fast(Pl[2][dglob][tok] + r_ * (a2 + b1h));
        float h = dh ? hc1 : hc0;
        if (tm >= 0) h = z * h + (1.0f - z) * hh;
        if (dh) hc1 = h; else hc0 = h;
        tr[(dglob >> 3) * 128 + row * 8 + (dglob & 7)] = f2h_bits(h);
      }
    }
    __syncthreads();                                   // S3

    if (w == 0) {
      // lane sl holds tr u16 idx sl*8+j = h[row=sl&15][kk=(sl>>4)*8+j],
      // exactly the consumer A-fragment order for dwords sl*8+j.
      u32x4 tr4 = ((const u32x4*)tr)[lane];
      u32 tag1 = ((u32)(t + 1)) << 16;
      u32x4 o0, o1;
      o0.x = tag1 | (tr4.x & 0xFFFFu); o0.y = tag1 | (tr4.x >> 16);
      o0.z = tag1 | (tr4.y & 0xFFFFu); o0.w = tag1 | (tr4.y >> 16);
      o1.x = tag1 | (tr4.z & 0xFFFFu); o1.y = tag1 | (tr4.z >> 16);
      o1.z = tag1 | (tr4.w & 0xFFFFu); o1.w = tag1 | (tr4.w >> 16);
      u32* eb = exch + (size_t)((t + 1) & (NSLOT - 1)) * SLOT_U32 +
                (size_t)(gt * 32 + ds) * 512 + lane * 8;
      // plain stores: land in the SHARED XCD L2 (fast path for same-XCD
      // consumers); sc1 stores: background write-through safety copy for
      // escalated (cross-XCD) consumers. Same data -> any order is fine.
      asm volatile("global_store_dwordx4 %0, %1, off\n\t"
                   "global_store_dwordx4 %0, %2, off offset:16\n\t"
                   "global_store_dwordx4 %0, %1, off sc1\n\t"
                   "global_store_dwordx4 %0, %2, off offset:16 sc1"
                   :: "v"(eb), "v"(o0), "v"(o1) : "memory");
      // Hout store off the critical path (visible at kernel completion)
      {
        int quad = lane >> 4, mm = lane & 15;
        int b = gt * 16 + mm;
        size_t idx = ((size_t)(b * 16 + (t >> 4)) * 32 + ds) * 64 +
                     quad * 16 + (t & 15);
        ((u32x4*)Hout)[idx] = tr4;
      }
    }
  }
}

// ---------- dense epilogue (unchanged; Hout layout identical) ----------
__global__ __launch_bounds__(256) void dense_mfma(
    const u16* __restrict__ HoutImg, const uint4* __restrict__ dimg,
    const float* __restrict__ dbf, void* __restrict__ out,
    const int* __restrict__ flag) {
  __shared__ uint4 Bl[48 * 64];
  int tid = threadIdx.x;
  int w = tid >> 6, lane = tid & 63;
  int quad = lane >> 4, vi = lane & 15;
  int gt0 = blockIdx.x * 8 + w * 2;

  f32x4 acc[2][3];
  #pragma unroll
  for (int i = 0; i < 2; ++i)
    #pragma unroll
    for (int c = 0; c < 3; ++c) acc[i][c] = (f32x4){0.f, 0.f, 0.f, 0.f};

  for (int half = 0; half < 2; ++half) {
    for (int i = tid; i < 48 * 64; i += 256) Bl[i] = dimg[half * 48 * 64 + i];
    __syncthreads();
    #pragma unroll
    for (int ks16 = 0; ks16 < 16; ++ks16) {
      int ks = half * 16 + ks16;
      f16x8 a0 = __builtin_bit_cast(
          f16x8, ((const uint4*)HoutImg)[((size_t)gt0 * 32 + ks) * 64 + lane]);
      f16x8 a1 = __builtin_bit_cast(
          f16x8, ((const uint4*)HoutImg)[(((size_t)gt0 + 1) * 32 + ks) * 64 + lane]);
      #pragma unroll
      for (int c = 0; c < 3; ++c) {
        f16x8 bf = __builtin_bit_cast(f16x8, Bl[(ks16 * 3 + c) * 64 + lane]);
        acc[0][c] = __builtin_amdgcn_mfma_f32_16x16x32_f16(a0, bf, acc[0][c], 0, 0, 0);
        acc[1][c] = __builtin_amdgcn_mfma_f32_16x16x32_f16(a1, bf, acc[1][c], 0, 0, 0);
      }
    }
    __syncthreads();
  }

  int isf = *flag;
  #pragma unroll
  for (int i = 0; i < 2; ++i) {
    #pragma unroll
    for (int c = 0; c < 3; ++c) {
      int v = c * 16 + vi;
      if (v >= VOCAB) continue;
      float bias = dbf[v];
      #pragma unroll
      for (int rg = 0; rg < 4; ++rg) {
        size_t bt = (size_t)(gt0 + i) * 16 + quad * 4 + rg;
        float val = acc[i][c][rg] + bias;
        if (isf) ((float*)out)[bt * VOCAB + v] = val;
        else     ((u16*)out)[bt * VOCAB + v] = f2bf(val);
      }
    }
  }
}

// ---------- launch ----------

extern "C" void kernel_launch(void* const* d_in, const int* in_sizes, int n_in,
                              void* d_out, int out_size, void* d_ws, size_t ws_size,
                              hipStream_t stream) {
  const int* x            = (const int*)d_in[0];
  const unsigned char* mk = (const unsigned char*)d_in[1];

  char* ws = (char*)d_ws;
  int*   flag  = (int*)(ws + 0);
  float* dbf   = (float*)(ws + 4 * 1024);
  float* gbf   = (float*)(ws + 8 * 1024);            // 24 KB
  int*   tokm  = (int*)(ws + 64 * 1024);             // 128 KB
  u16*   dimg  = (u16*)(ws + 192 * 1024);            // 96 KB
  float* P     = (float*)(ws + 288 * 1024);          // 504 KB
  float* P2    = (float*)(ws + 800 * 1024);          // 504 KB
  u32*   exch  = (u32*)(ws + 1312 * 1024);           // 2 MB (4 slots x 512 KB)
  u16*   Wimg  = (u16*)(ws + 3456 * 1024);           // 6 MB
  u16*   Hout  = (u16*)(ws + 10 * 1024 * 1024);      // 64 MB

  detect_kernel<<<1, 256, 0, stream>>>((const u16*)d_in[4], flag);
  conv_kernel<<<(2 * H3 + 255) / 256, 256, 0, stream>>>(d_in[5], gbf, 2 * H3, flag);
  conv_kernel<<<1, 256, 0, stream>>>(d_in[7], dbf, VOCAB, flag);
  tokm_kernel<<<BT / 256, 256, 0, stream>>>(x, mk, tokm);
  proj_kernel<<<VOCAB * (H3 / 256), 256, 0, stream>>>(d_in[2], d_in[3], gbf, P, flag);
  p2_kernel<<<H3, 64, 0, stream>>>(P, gbf, P2);
  pack_wimg_kernel<<<(32 * 32 * 6 * 64 * 8) / 256, 256, 0, stream>>>(d_in[4], Wimg, flag);
  pack_dimg_kernel<<<(32 * 3 * 64 * 8) / 256, 256, 0, stream>>>(d_in[6], dimg, flag);
  // slot 0 = h_0 = zeros with tag 0; other slots zero => tag 0 never
  // matches their expected tags (t>=1).
  hipMemsetAsync(exch, 0, (size_t)NSLOT * SLOT_U32 * 4, stream);

  gru_persist<<<256, 256, 0, stream>>>((const uint4*)Wimg, tokm, P2, gbf,
                                       exch, Hout);
  dense_mfma<<<256, 256, 0, stream>>>(Hout, (const uint4*)dimg, dbf, d_out, flag);
}

// Round 3
// 1110.936 us; speedup vs baseline: 1.3527x; 1.3527x over previous
//
#include <hip/hip_runtime.h>
#include <stdint.h>
#include <stddef.h>

#define VOCAB 41
#define EMB   512
#define HID   1024
#define H3    3072
#define BB    128
#define TT    256
#define BT    (BB*TT)
#define NSLOT 3
#define SLOT_U32 8192          // per (gt,slot): 32 producers x 256 dwords = 32 KB

typedef unsigned short u16;
typedef uint32_t u32;
typedef _Float16 half_t;
typedef half_t f16x8 __attribute__((ext_vector_type(8)));
typedef float f32x4 __attribute__((ext_vector_type(4)));
typedef u32 u32x4 __attribute__((ext_vector_type(4)));

__device__ __forceinline__ float bf2f(u16 u) {
  return __uint_as_float(((uint32_t)u) << 16);
}
__device__ __forceinline__ u16 f2bf(float f) {
  uint32_t x = __float_as_uint(f);
  return (u16)((x + 0x7FFFu + ((x >> 16) & 1u)) >> 16);
}
__device__ __forceinline__ u16 f2h_bits(float f) {
  half_t h = (half_t)f;
  return __builtin_bit_cast(u16, h);
}
__device__ __forceinline__ float sigmoidf_(float x) {
  return 1.0f / (1.0f + __expf(-x));
}
__device__ __forceinline__ float tanh_fast(float x) {
  return 1.0f - 2.0f / (__expf(2.0f * x) + 1.0f);
}

// ---------- prologue kernels ----------

__global__ void detect_kernel(const u16* __restrict__ raw, int* __restrict__ flag) {
  __shared__ int s[256];
  int tid = threadIdx.x, cnt = 0;
  for (int i = tid; i < 4096; i += 256) {
    int e = (raw[i] >> 7) & 0xFF;
    if (e >= 132) cnt++;
  }
  s[tid] = cnt; __syncthreads();
  if (tid == 0) {
    int tot = 0;
    for (int i = 0; i < 256; i++) tot += s[i];
    *flag = (tot > 4) ? 1 : 0;
  }
}

__global__ void conv_kernel(const void* __restrict__ src, float* __restrict__ dst,
                            int n, const int* __restrict__ flag) {
  int i = blockIdx.x * 256 + threadIdx.x;
  if (i >= n) return;
  if (*flag) dst[i] = ((const float*)src)[i];
  else       dst[i] = bf2f(((const u16*)src)[i]);
}

__global__ void tokm_kernel(const int* __restrict__ x,
                            const unsigned char* __restrict__ m,
                            int* __restrict__ tokm) {
  int i = blockIdx.x * 256 + threadIdx.x;
  unsigned char b0 = m[0], b1 = m[1];
  bool t;
  if (b0 == 1) {
    if (b1 != 0) t = (m[i] != 0);
    else         t = (((const int*)m)[i] != 0);
  } else if (b0 == 0x80) {
    t = (((const u16*)m)[i] != 0);
  } else {
    t = (((const float*)m)[i] != 0.0f);
  }
  tokm[i] = x[i] | (t ? 0 : 0x80000000);
}

__global__ __launch_bounds__(256) void proj_kernel(
    const void* __restrict__ emb, const void* __restrict__ gk,
    const float* __restrict__ gbf, float* __restrict__ P,
    const int* __restrict__ flag) {
  int v = blockIdx.x / (H3 / 256);
  int j = (blockIdx.x % (H3 / 256)) * 256 + threadIdx.x;
  float acc = gbf[j];
  if (*flag) {
    const float* e = (const float*)emb + v * EMB;
    const float* g = (const float*)gk;
    for (int k = 0; k < EMB; ++k) acc = fmaf(e[k], g[k * H3 + j], acc);
  } else {
    const u16* e = (const u16*)emb + v * EMB;
    const u16* g = (const u16*)gk;
    for (int k = 0; k < EMB; ++k) acc = fmaf(bf2f(e[k]), bf2f(g[k * H3 + j]), acc);
  }
  P[v * H3 + j] = acc;
}

__global__ void p2_kernel(const float* __restrict__ P, const float* __restrict__ gbf,
                          float* __restrict__ P2) {
  int gc = blockIdx.x;
  int v = threadIdx.x;
  if (v >= VOCAB) return;
  float val = P[v * H3 + gc];
  if (gc < 2048) val += gbf[H3 + gc];
  P2[gc * VOCAB + v] = val;
}

// Fat-block Wimg: [ds 0..31][ks 0..31][c 0..5][lane][j], c = g*2 + dh,
// col = g*1024 + ds*32 + dh*16 + (lane&15), k = ks*32 + (lane>>4)*8 + j.
__global__ void pack_wimg_kernel(const void* __restrict__ src, u16* __restrict__ img,
                                 const int* __restrict__ flag) {
  int idx = blockIdx.x * 256 + threadIdx.x;       // 0 .. 3,145,727
  int j = idx & 7;
  int t1 = idx >> 3;
  int lane = t1 & 63;
  int t2 = t1 >> 6;
  int c = t2 % 6;
  int t3 = t2 / 6;
  int ks = t3 & 31;
  int ds = t3 >> 5;
  int g = c >> 1, dh = c & 1;
  int k = ks * 32 + (lane >> 4) * 8 + j;
  int col = g * 1024 + ds * 32 + dh * 16 + (lane & 15);
  float val;
  if (*flag) val = ((const float*)src)[(size_t)k * H3 + col];
  else       val = bf2f(((const u16*)src)[(size_t)k * H3 + col]);
  img[idx] = f2h_bits(val);
}

__global__ void pack_dimg_kernel(const void* __restrict__ src, u16* __restrict__ img,
                                 const int* __restrict__ flag) {
  int idx = blockIdx.x * 256 + threadIdx.x;
  int j = idx & 7;
  int t1 = idx >> 3;
  int lane = t1 & 63;
  int t2 = t1 >> 6;
  int ct = t2 % 3;
  int ks = t2 / 3;
  int k = ks * 32 + (lane >> 4) * 8 + j;
  int v = ct * 16 + (lane & 15);
  float val = 0.0f;
  if (v < VOCAB) {
    if (*flag) val = ((const float*)src)[(size_t)k * VOCAB + v];
    else       val = bf2f(((const u16*)src)[(size_t)k * VOCAB + v]);
  }
  img[idx] = f2h_bits(val);
}

// ---------- persistent GRU: XCD-local exchange, free-bit tags -----------
// 256 blocks x 256 thr (1/CU). Roles assigned at RUNTIME from the real
// XCD id (s_getreg HW_REG_XCC_ID, measured working on MI355X): all 32
// blocks of a gt group share ONE XCD L2 by construction. Exchange is then
// SE-scope: plain stores (dirty in shared L2) + sc0 loads (L1-bypass,
// L2-hit ~200cyc). No MALL/HBM round trip, no drain, no flags.
//
// Tags are FREE: |h| <= 1 (GRU invariant, h0=0) => f16 bit14 == 0 always.
// Each dword (2 f16) embeds a 2-bit step tag at bits {14,30}. Dword
// single-copy atomicity => tag match guarantees same-step data. NSLOT=3:
// only distance-3 staleness is reachable (group lockstep: consume-before-
// produce bounds skew to 1 step), and (tau-3)&3 != tau&3 always.
//
// Placement safety: groups with member-count != 32 (misplaced blocks)
// switch wholesale to sc1 write-through (R1-proven protocol). Stuck
// consumers escalate to alternating sc0/sc1 polls. Correctness never
// depends on placement; only speed does.
__global__ __launch_bounds__(256, 1) void gru_persist(
    const uint4* __restrict__ Wimg, const int* __restrict__ tokm,
    const float* __restrict__ P2, const float* __restrict__ gbf,
    u32* __restrict__ exch, u16* __restrict__ Hout,
    int* __restrict__ rolectl) {
  int tid = threadIdx.x;
  int w = tid >> 6, lane = tid & 63;

  __shared__ float red[4][64][25];     // 24 acc floats/lane, pad 25
  __shared__ __align__(16) u16 tr[512];   // 16 rows x 32 dims
  __shared__ float Pl[3][32][41];
  __shared__ int tokL[16 * 259];
  __shared__ int roleS;

  // ---- runtime role assignment: gt group == physical XCD ----
  if (tid == 0) {
    u32 xcd;
    asm volatile("s_getreg_b32 %0, hwreg(HW_REG_XCC_ID)" : "=s"(xcd));
    xcd &= 7;
    int r = __hip_atomic_fetch_add(rolectl + xcd, 1, __ATOMIC_RELAXED,
                                   __HIP_MEMORY_SCOPE_AGENT);
    int role;
    if (r < 32) role = (int)xcd * 32 + r;
    else {
      int o = __hip_atomic_fetch_add(rolectl + 8, 1, __ATOMIC_RELAXED,
                                     __HIP_MEMORY_SCOPE_AGENT);
      role = -2 - o;                   // overflow ticket
    }
    __hip_atomic_fetch_add(rolectl + 9, 1, __ATOMIC_RELAXED,
                           __HIP_MEMORY_SCOPE_AGENT);
    while (__hip_atomic_load(rolectl + 9, __ATOMIC_RELAXED,
                             __HIP_MEMORY_SCOPE_AGENT) < 256)
      __builtin_amdgcn_s_sleep(8);
    if (role < 0) {                    // claim o-th free slot (underfull groups)
      int o = -2 - role, seen = 0;
      for (int g = 0; g < 8; ++g) {
        int c = __hip_atomic_load(rolectl + g, __ATOMIC_RELAXED,
                                  __HIP_MEMORY_SCOPE_AGENT);
        int cc = c > 32 ? 32 : c;
        int nf = 32 - cc;
        if (o < seen + nf) { role = g * 32 + cc + (o - seen); break; }
        seen += nf;
      }
    }
    int cg = __hip_atomic_load(rolectl + (role >> 5), __ATOMIC_RELAXED,
                               __HIP_MEMORY_SCOPE_AGENT);
    int dirty = (cg < 32) ? 1 : 0;     // group has cross-XCD members
    roleS = role | (dirty << 16);
  }
  __syncthreads();
  int role = roleS & 0xFFFF;
  int dirty = roleS >> 16;
  int gt = role >> 5, ds = role & 31;

  // persistent B fragments: 6 tiles x 8 k-steps (this wave's K-quarter)
  f16x8 breg[6][8];
  {
    const uint4* wsrc = Wimg + (size_t)ds * (32 * 6) * 64 + lane;
    #pragma unroll
    for (int k8 = 0; k8 < 8; ++k8)
      #pragma unroll
      for (int c = 0; c < 6; ++c)
        breg[c][k8] = __builtin_bit_cast(f16x8, wsrc[((w * 8 + k8) * 6 + c) * 64]);
  }

  // preload epilogue tables: P2 slice (3x32x41) and token map (16x256)
  for (int i = tid; i < 3 * 32 * VOCAB; i += 256) {
    int v = i % VOCAB;
    int t1 = i / VOCAB;
    int di = t1 & 31, g = t1 >> 5;
    Pl[g][di][v] = P2[(size_t)(g * 1024 + ds * 32 + di) * VOCAB + v];
  }
  for (int i = tid; i < 16 * 256; i += 256) {
    int rr = i >> 8, cc = i & 255;
    tokL[rr * 259 + cc] = tokm[gt * 4096 + i];
  }

  // per-thread epilogue ownership: (row, dimb) and (row, dimb+16)
  int row = tid >> 4, dimb = tid & 15;
  int lane_src = (row >> 2) * 16 + dimb;
  int rg = row & 3;
  float b1h0 = gbf[H3 + 2048 + ds * 32 + dimb];
  float b1h1 = gbf[H3 + 2048 + ds * 32 + dimb + 16];
  float hc0 = 0.f, hc1 = 0.f;
  __syncthreads();                     // protect LDS preloads

  int coh = dirty;                     // sticky: 0 = sc0 L2 path, 1 = escalated
  int slot_c = 0, slot_p = 1;
  u32x4 d[8];
  for (int t = 0; t < TT; ++t) {
    const u32* slotb = exch + (size_t)(gt * 3 + slot_c) * SLOT_U32;
    const u32* abase = slotb + (size_t)(w * 8) * 256 + lane * 4;
    // sentinel: 8 producers x 8 lanes, one dword per 128B line
    const u32* sp = slotb + (size_t)(w * 8 + (lane >> 3)) * 256 +
                    (lane & 7) * 32 + 31;
    u32 texp = ((u32)(t & 1) << 14) | ((u32)(t & 2) << 29);
    int tries = 0;
    while (true) {
      int m = coh & (tries & 1);       // escalated: alternate sc0 / sc1
      u32 v;
      if (!m)
        asm volatile("global_load_dword %0, %1, off sc0\n\ts_waitcnt vmcnt(0)"
                     : "=v"(v) : "v"(sp) : "memory");
      else
        asm volatile("global_load_dword %0, %1, off sc1\n\ts_waitcnt vmcnt(0)"
                     : "=v"(v) : "v"(sp) : "memory");
      __builtin_amdgcn_sched_barrier(0);
      if (__ballot((v & 0x40004000u) != texp) == 0ULL) {
        if (!m) {
          #pragma unroll
          for (int i = 0; i < 8; ++i)
            asm volatile("global_load_dwordx4 %0, %1, off sc0"
                         : "=v"(d[i]) : "v"(abase + (size_t)i * 256) : "memory");
        } else {
          #pragma unroll
          for (int i = 0; i < 8; ++i)
            asm volatile("global_load_dwordx4 %0, %1, off sc1"
                         : "=v"(d[i]) : "v"(abase + (size_t)i * 256) : "memory");
        }
        asm volatile("s_waitcnt vmcnt(0)" ::: "memory");
        __builtin_amdgcn_sched_barrier(0);
        u32 bad = 0;
        #pragma unroll
        for (int i = 0; i < 8; ++i) {
          u32x4 q = d[i];
          bad |= (q.x ^ texp) | (q.y ^ texp) | (q.z ^ texp) | (q.w ^ texp);
        }
        bad &= 0x40004000u;
        if (__ballot(bad != 0) == 0ULL) break;
      }
      __builtin_amdgcn_s_sleep(1);
      if (++tries > 512) coh = 1;      // placement-proof escalation
      if (tries > (1 << 17)) break;    // fail loud (absmax) instead of hang
    }

    // --- strip tag bits (bit14 of each f16 is 0 for |h|<=1) + MFMA ---
    f32x4 acc[6];
    #pragma unroll
    for (int c = 0; c < 6; ++c) acc[c] = (f32x4){0.f, 0.f, 0.f, 0.f};
    #pragma unroll
    for (int k8 = 0; k8 < 8; ++k8) {
      u32x4 q = d[k8] & 0xBFFFBFFFu;
      f16x8 a = __builtin_bit_cast(f16x8, q);
      #pragma unroll
      for (int c = 0; c < 6; ++c)
        acc[c] = __builtin_amdgcn_mfma_f32_16x16x32_f16(a, breg[c][k8], acc[c], 0, 0, 0);
    }

    {
      float* q = red[w][lane];
      #pragma unroll
      for (int c = 0; c < 6; ++c)
        #pragma unroll
        for (int r = 0; r < 4; ++r) q[c * 4 + r] = acc[c][r];
    }
    __syncthreads();                                   // S2

    // per-thread reduce over 4 K-quarters + gate epilogue (2 dims)
    {
      int tm = tokL[row * 259 + t];
      int tok = tm & 0xFFFF;
      #pragma unroll
      for (int dh = 0; dh < 2; ++dh) {
        float a0 = 0.f, a1 = 0.f, a2 = 0.f;
        #pragma unroll
        for (int ww = 0; ww < 4; ++ww) {
          const float* q = red[ww][lane_src];
          a0 += q[(0 * 2 + dh) * 4 + rg];
          a1 += q[(1 * 2 + dh) * 4 + rg];
          a2 += q[(2 * 2 + dh) * 4 + rg];
        }
        int dglob = dimb + dh * 16;
        float z  = sigmoidf_(Pl[0][dglob][tok] + a0);
        float r_ = sigmoidf_(Pl[1][dglob][tok] + a1);
        float b1h = dh ? b1h1 : b1h0;
        float hh = tanh_fast(Pl[2][dglob][tok] + r_ * (a2 + b1h));
        float h = dh ? hc1 : hc0;
        if (tm >= 0) h = z * h + (1.0f - z) * hh;
        if (dh) hc1 = h; else hc0 = h;
        tr[(dglob >> 3) * 128 + row * 8 + (dglob & 7)] = f2h_bits(h);
      }
    }
    __syncthreads();                                   // S3

    if (w == 0) {
      // lane sl holds tr u16 idx sl*8+j = h[row=sl&15][kk=(sl>>4)*8+j],
      // exactly the consumer A-fragment order (verified R1).
      u32x4 tr4 = ((const u32x4*)tr)[lane];
      u32 tmask = ((u32)((t + 1) & 1) << 14) | ((u32)((t + 1) & 2) << 29);
      u32x4 o = tr4 | tmask;
      u32* eb = exch + (size_t)(gt * 3 + slot_p) * SLOT_U32 + ds * 256 + lane * 4;
      if (!dirty)
        asm volatile("global_store_dwordx4 %0, %1, off"
                     :: "v"(eb), "v"(o) : "memory");     // dirty in shared L2
      else
        asm volatile("global_store_dwordx4 %0, %1, off sc1"
                     :: "v"(eb), "v"(o) : "memory");     // write-through (safe)
      // Hout store (untagged) off the critical path
      {
        int quad = lane >> 4, mm = lane & 15;
        int b = gt * 16 + mm;
        size_t idx = ((size_t)(b * 16 + (t >> 4)) * 32 + ds) * 64 +
                     quad * 16 + (t & 15);
        ((u32x4*)Hout)[idx] = tr4;
      }
    }
    slot_c = slot_p;
    slot_p = (slot_p == 2) ? 0 : slot_p + 1;
  }
}

// ---------- dense epilogue (unchanged; Hout layout identical) ----------
__global__ __launch_bounds__(256) void dense_mfma(
    const u16* __restrict__ HoutImg, const uint4* __restrict__ dimg,
    const float* __restrict__ dbf, void* __restrict__ out,
    const int* __restrict__ flag) {
  __shared__ uint4 Bl[48 * 64];
  int tid = threadIdx.x;
  int w = tid >> 6, lane = tid & 63;
  int quad = lane >> 4, vi = lane & 15;
  int gt0 = blockIdx.x * 8 + w * 2;

  f32x4 acc[2][3];
  #pragma unroll
  for (int i = 0; i < 2; ++i)
    #pragma unroll
    for (int c = 0; c < 3; ++c) acc[i][c] = (f32x4){0.f, 0.f, 0.f, 0.f};

  for (int half = 0; half < 2; ++half) {
    for (int i = tid; i < 48 * 64; i += 256) Bl[i] = dimg[half * 48 * 64 + i];
    __syncthreads();
    #pragma unroll
    for (int ks16 = 0; ks16 < 16; ++ks16) {
      int ks = half * 16 + ks16;
      f16x8 a0 = __builtin_bit_cast(
          f16x8, ((const uint4*)HoutImg)[((size_t)gt0 * 32 + ks) * 64 + lane]);
      f16x8 a1 = __builtin_bit_cast(
          f16x8, ((const uint4*)HoutImg)[(((size_t)gt0 + 1) * 32 + ks) * 64 + lane]);
      #pragma unroll
      for (int c = 0; c < 3; ++c) {
        f16x8 bf = __builtin_bit_cast(f16x8, Bl[(ks16 * 3 + c) * 64 + lane]);
        acc[0][c] = __builtin_amdgcn_mfma_f32_16x16x32_f16(a0, bf, acc[0][c], 0, 0, 0);
        acc[1][c] = __builtin_amdgcn_mfma_f32_16x16x32_f16(a1, bf, acc[1][c], 0, 0, 0);
      }
    }
    __syncthreads();
  }

  int isf = *flag;
  #pragma unroll
  for (int i = 0; i < 2; ++i) {
    #pragma unroll
    for (int c = 0; c < 3; ++c) {
      int v = c * 16 + vi;
      if (v >= VOCAB) continue;
      float bias = dbf[v];
      #pragma unroll
      for (int rg = 0; rg < 4; ++rg) {
        size_t bt = (size_t)(gt0 + i) * 16 + quad * 4 + rg;
        float val = acc[i][c][rg] + bias;
        if (isf) ((float*)out)[bt * VOCAB + v] = val;
        else     ((u16*)out)[bt * VOCAB + v] = f2bf(val);
      }
    }
  }
}

// ---------- launch ----------

extern "C" void kernel_launch(void* const* d_in, const int* in_sizes, int n_in,
                              void* d_out, int out_size, void* d_ws, size_t ws_size,
                              hipStream_t stream) {
  const int* x            = (const int*)d_in[0];
  const unsigned char* mk = (const unsigned char*)d_in[1];

  char* ws = (char*)d_ws;
  int*   flag    = (int*)(ws + 0);
  float* dbf     = (float*)(ws + 4 * 1024);
  float* gbf     = (float*)(ws + 8 * 1024);          // 24 KB
  int*   rolectl = (int*)(ws + 32 * 1024);           // 64 B role counters
  int*   tokm    = (int*)(ws + 64 * 1024);           // 128 KB
  u16*   dimg    = (u16*)(ws + 192 * 1024);          // 96 KB
  float* P       = (float*)(ws + 288 * 1024);        // 504 KB
  float* P2      = (float*)(ws + 800 * 1024);        // 504 KB
  u32*   exch    = (u32*)(ws + 1312 * 1024);         // 768 KB (8 gt x 3 x 32 KB)
  u16*   Wimg    = (u16*)(ws + 3456 * 1024);         // 6 MB
  u16*   Hout    = (u16*)(ws + 10 * 1024 * 1024);    // 64 MB

  detect_kernel<<<1, 256, 0, stream>>>((const u16*)d_in[4], flag);
  conv_kernel<<<(2 * H3 + 255) / 256, 256, 0, stream>>>(d_in[5], gbf, 2 * H3, flag);
  conv_kernel<<<1, 256, 0, stream>>>(d_in[7], dbf, VOCAB, flag);
  tokm_kernel<<<BT / 256, 256, 0, stream>>>(x, mk, tokm);
  proj_kernel<<<VOCAB * (H3 / 256), 256, 0, stream>>>(d_in[2], d_in[3], gbf, P, flag);
  p2_kernel<<<H3, 64, 0, stream>>>(P, gbf, P2);
  pack_wimg_kernel<<<(32 * 32 * 6 * 64 * 8) / 256, 256, 0, stream>>>(d_in[4], Wimg, flag);
  pack_dimg_kernel<<<(32 * 3 * 64 * 8) / 256, 256, 0, stream>>>(d_in[6], dimg, flag);
  // slot 0 zeros = h_0 = 0 with tag 0; slots 1,2 zeros never match tags 1,2.
  hipMemsetAsync(exch, 0, (size_t)8 * NSLOT * SLOT_U32 * 4, stream);
  hipMemsetAsync(rolectl, 0, 64, stream);

  gru_persist<<<256, 256, 0, stream>>>((const uint4*)Wimg, tokm, P2, gbf,
                                       exch, Hout, rolectl);
  dense_mfma<<<256, 256, 0, stream>>>(Hout, (const uint4*)dimg, dbf, d_out, flag);
}

// Round 4
// 1002.967 us; speedup vs baseline: 1.4983x; 1.1076x over previous
//
#include <hip/hip_runtime.h>
#include <stdint.h>
#include <stddef.h>

#define VOCAB 41
#define EMB   512
#define HID   1024
#define H3    3072
#define BB    128
#define TT    256
#define BT    (BB*TT)
#define NSLOT 3
#define SLOT_U32 8192          // per (gt,slot): 32 producers x 256 dwords = 32 KB

typedef unsigned short u16;
typedef uint32_t u32;
typedef _Float16 half_t;
typedef half_t f16x8 __attribute__((ext_vector_type(8)));
typedef float f32x4 __attribute__((ext_vector_type(4)));
typedef u32 u32x4 __attribute__((ext_vector_type(4)));

__device__ __forceinline__ float bf2f(u16 u) {
  return __uint_as_float(((uint32_t)u) << 16);
}
__device__ __forceinline__ u16 f2bf(float f) {
  uint32_t x = __float_as_uint(f);
  return (u16)((x + 0x7FFFu + ((x >> 16) & 1u)) >> 16);
}
__device__ __forceinline__ u16 f2h_bits(float f) {
  half_t h = (half_t)f;
  return __builtin_bit_cast(u16, h);
}
__device__ __forceinline__ float sigmoidf_(float x) {
  return 1.0f / (1.0f + __expf(-x));
}
__device__ __forceinline__ float tanh_fast(float x) {
  return 1.0f - 2.0f / (__expf(2.0f * x) + 1.0f);
}

// ---------- prologue kernels ----------

__global__ void detect_kernel(const u16* __restrict__ raw, int* __restrict__ flag) {
  __shared__ int s[256];
  int tid = threadIdx.x, cnt = 0;
  for (int i = tid; i < 4096; i += 256) {
    int e = (raw[i] >> 7) & 0xFF;
    if (e >= 132) cnt++;
  }
  s[tid] = cnt; __syncthreads();
  if (tid == 0) {
    int tot = 0;
    for (int i = 0; i < 256; i++) tot += s[i];
    *flag = (tot > 4) ? 1 : 0;
  }
}

__global__ void conv_kernel(const void* __restrict__ src, float* __restrict__ dst,
                            int n, const int* __restrict__ flag) {
  int i = blockIdx.x * 256 + threadIdx.x;
  if (i >= n) return;
  if (*flag) dst[i] = ((const float*)src)[i];
  else       dst[i] = bf2f(((const u16*)src)[i]);
}

__global__ void tokm_kernel(const int* __restrict__ x,
                            const unsigned char* __restrict__ m,
                            int* __restrict__ tokm) {
  int i = blockIdx.x * 256 + threadIdx.x;
  unsigned char b0 = m[0], b1 = m[1];
  bool t;
  if (b0 == 1) {
    if (b1 != 0) t = (m[i] != 0);
    else         t = (((const int*)m)[i] != 0);
  } else if (b0 == 0x80) {
    t = (((const u16*)m)[i] != 0);
  } else {
    t = (((const float*)m)[i] != 0.0f);
  }
  tokm[i] = x[i] | (t ? 0 : 0x80000000);
}

__global__ __launch_bounds__(256) void proj_kernel(
    const void* __restrict__ emb, const void* __restrict__ gk,
    const float* __restrict__ gbf, float* __restrict__ P,
    const int* __restrict__ flag) {
  int v = blockIdx.x / (H3 / 256);
  int j = (blockIdx.x % (H3 / 256)) * 256 + threadIdx.x;
  float acc = gbf[j];
  if (*flag) {
    const float* e = (const float*)emb + v * EMB;
    const float* g = (const float*)gk;
    for (int k = 0; k < EMB; ++k) acc = fmaf(e[k], g[k * H3 + j], acc);
  } else {
    const u16* e = (const u16*)emb + v * EMB;
    const u16* g = (const u16*)gk;
    for (int k = 0; k < EMB; ++k) acc = fmaf(bf2f(e[k]), bf2f(g[k * H3 + j]), acc);
  }
  P[v * H3 + j] = acc;
}

__global__ void p2_kernel(const float* __restrict__ P, const float* __restrict__ gbf,
                          float* __restrict__ P2) {
  int gc = blockIdx.x;
  int v = threadIdx.x;
  if (v >= VOCAB) return;
  float val = P[v * H3 + gc];
  if (gc < 2048) val += gbf[H3 + gc];
  P2[gc * VOCAB + v] = val;
}

// Fat-block Wimg: [ds 0..31][ks 0..31][c 0..5][lane][j], c = g*2 + dh,
// col = g*1024 + ds*32 + dh*16 + (lane&15), k = ks*32 + (lane>>4)*8 + j.
__global__ void pack_wimg_kernel(const void* __restrict__ src, u16* __restrict__ img,
                                 const int* __restrict__ flag) {
  int idx = blockIdx.x * 256 + threadIdx.x;       // 0 .. 3,145,727
  int j = idx & 7;
  int t1 = idx >> 3;
  int lane = t1 & 63;
  int t2 = t1 >> 6;
  int c = t2 % 6;
  int t3 = t2 / 6;
  int ks = t3 & 31;
  int ds = t3 >> 5;
  int g = c >> 1, dh = c & 1;
  int k = ks * 32 + (lane >> 4) * 8 + j;
  int col = g * 1024 + ds * 32 + dh * 16 + (lane & 15);
  float val;
  if (*flag) val = ((const float*)src)[(size_t)k * H3 + col];
  else       val = bf2f(((const u16*)src)[(size_t)k * H3 + col]);
  img[idx] = f2h_bits(val);
}

__global__ void pack_dimg_kernel(const void* __restrict__ src, u16* __restrict__ img,
                                 const int* __restrict__ flag) {
  int idx = blockIdx.x * 256 + threadIdx.x;
  int j = idx & 7;
  int t1 = idx >> 3;
  int lane = t1 & 63;
  int t2 = t1 >> 6;
  int ct = t2 % 3;
  int ks = t2 / 3;
  int k = ks * 32 + (lane >> 4) * 8 + j;
  int v = ct * 16 + (lane & 15);
  float val = 0.0f;
  if (v < VOCAB) {
    if (*flag) val = ((const float*)src)[(size_t)k * VOCAB + v];
    else       val = bf2f(((const u16*)src)[(size_t)k * VOCAB + v]);
  }
  img[idx] = f2h_bits(val);
}

// ---------- persistent GRU: XCD-local exchange, doorbell + free-bit tags
// 256 blocks x 256 thr (1/CU). Runtime XCD roles (R3, verified: FETCH
// collapsed 111->27MB): all 32 blocks of a gt group share one XCD L2.
//
// R4 changes (theory: R3's 64-line/wave sentinel polls saturated the XCD
// L2 request pipe -- 128 waves x 64 lines / ~300cyc ~ 27 req/cyc -- and
// the polling itself delayed the stores/loads being polled for):
//  1. DOORBELL: per (gt, K-quarter) one 128B line of 8 monotonic
//     per-producer counters (plain dword stores, no RMW, no reset).
//     Consumer wave polls ONE line. Doorbell is a hint only; correctness
//     still from per-dword tag verify on the bulk load (order-proof).
//  2. Hout per-step scattered stores -> 16-step LDS history (trH),
//     flushed every 16 steps as coalesced 1KB runs by all 4 waves.
//     De-pollutes the spin loop's vmcnt(0) and the L2/HBM write path.
// Tags unchanged: |h|<=1 => f16 bit14==0; 2-bit step tag at dword bits
// {14,30}; NSLOT=3 makes every reachable staleness distance tag-distinct.
__global__ __launch_bounds__(256, 1) void gru_persist(
    const uint4* __restrict__ Wimg, const int* __restrict__ tokm,
    const float* __restrict__ P2, const float* __restrict__ gbf,
    u32* __restrict__ exch, u16* __restrict__ Hout,
    int* __restrict__ rolectl, u32* __restrict__ db) {
  int tid = threadIdx.x;
  int w = tid >> 6, lane = tid & 63;

  __shared__ float red[4][64][25];     // 24 acc floats/lane, pad 25
  __shared__ __align__(16) u16 trH[16 * 512];  // 16-step h history
  __shared__ float Pl[3][32][41];
  __shared__ int tokL[16 * 259];
  __shared__ int roleS;

  // ---- runtime role assignment: gt group == physical XCD ----
  if (tid == 0) {
    u32 xcd;
    asm volatile("s_getreg_b32 %0, hwreg(HW_REG_XCC_ID)" : "=s"(xcd));
    xcd &= 7;
    int r = __hip_atomic_fetch_add(rolectl + xcd, 1, __ATOMIC_RELAXED,
                                   __HIP_MEMORY_SCOPE_AGENT);
    int role;
    if (r < 32) role = (int)xcd * 32 + r;
    else {
      int o = __hip_atomic_fetch_add(rolectl + 8, 1, __ATOMIC_RELAXED,
                                     __HIP_MEMORY_SCOPE_AGENT);
      role = -2 - o;                   // overflow ticket
    }
    __hip_atomic_fetch_add(rolectl + 9, 1, __ATOMIC_RELAXED,
                           __HIP_MEMORY_SCOPE_AGENT);
    while (__hip_atomic_load(rolectl + 9, __ATOMIC_RELAXED,
                             __HIP_MEMORY_SCOPE_AGENT) < 256)
      __builtin_amdgcn_s_sleep(8);
    if (role < 0) {                    // claim o-th free slot (underfull groups)
      int o = -2 - role, seen = 0;
      for (int g = 0; g < 8; ++g) {
        int c = __hip_atomic_load(rolectl + g, __ATOMIC_RELAXED,
                                  __HIP_MEMORY_SCOPE_AGENT);
        int cc = c > 32 ? 32 : c;
        int nf = 32 - cc;
        if (o < seen + nf) { role = g * 32 + cc + (o - seen); break; }
        seen += nf;
      }
    }
    int cg = __hip_atomic_load(rolectl + (role >> 5), __ATOMIC_RELAXED,
                               __HIP_MEMORY_SCOPE_AGENT);
    int dirty = (cg < 32) ? 1 : 0;     // group has cross-XCD members
    roleS = role | (dirty << 16);
  }
  __syncthreads();
  int role = roleS & 0xFFFF;
  int dirty = roleS >> 16;
  int gt = role >> 5, ds = role & 31;

  // persistent B fragments: 6 tiles x 8 k-steps (this wave's K-quarter)
  f16x8 breg[6][8];
  {
    const uint4* wsrc = Wimg + (size_t)ds * (32 * 6) * 64 + lane;
    #pragma unroll
    for (int k8 = 0; k8 < 8; ++k8)
      #pragma unroll
      for (int c = 0; c < 6; ++c)
        breg[c][k8] = __builtin_bit_cast(f16x8, wsrc[((w * 8 + k8) * 6 + c) * 64]);
  }

  // preload epilogue tables: P2 slice (3x32x41) and token map (16x256)
  for (int i = tid; i < 3 * 32 * VOCAB; i += 256) {
    int v = i % VOCAB;
    int t1 = i / VOCAB;
    int di = t1 & 31, g = t1 >> 5;
    Pl[g][di][v] = P2[(size_t)(g * 1024 + ds * 32 + di) * VOCAB + v];
  }
  for (int i = tid; i < 16 * 256; i += 256) {
    int rr = i >> 8, cc = i & 255;
    tokL[rr * 259 + cc] = tokm[gt * 4096 + i];
  }

  // per-thread epilogue ownership: (row, dimb) and (row, dimb+16)
  int row = tid >> 4, dimb = tid & 15;
  int lane_src = (row >> 2) * 16 + dimb;
  int rg = row & 3;
  float b1h0 = gbf[H3 + 2048 + ds * 32 + dimb];
  float b1h1 = gbf[H3 + 2048 + ds * 32 + dimb + 16];
  float hc0 = 0.f, hc1 = 0.f;
  __syncthreads();                     // protect LDS preloads

  int coh = dirty;                     // sticky: 0 = sc0 L2 path, 1 = escalated
  int slot_c = 0, slot_p = 1;
  // doorbell: wave w watches quarter w of its group -- ONE 128B line
  const u32* dbq = db + (size_t)(gt * 4 + w) * 32 + (lane & 7);
  u32x4 d[8];
  for (int t = 0; t < TT; ++t) {
    const u32* slotb = exch + (size_t)(gt * 3 + slot_c) * SLOT_U32;
    const u32* abase = slotb + (size_t)(w * 8) * 256 + lane * 4;
    u32 texp = ((u32)(t & 1) << 14) | ((u32)(t & 2) << 29);
    u32 tth = (u32)t;
    int tries = 0;
    while (true) {
      int m = coh & (tries & 1);       // escalated: alternate sc0 / sc1
      u32 v;
      if (!m)
        asm volatile("global_load_dword %0, %1, off sc0\n\ts_waitcnt vmcnt(0)"
                     : "=v"(v) : "v"(dbq) : "memory");
      else
        asm volatile("global_load_dword %0, %1, off sc1\n\ts_waitcnt vmcnt(0)"
                     : "=v"(v) : "v"(dbq) : "memory");
      __builtin_amdgcn_sched_barrier(0);
      if (__ballot(v < tth) == 0ULL) {
        // bulk load + full per-dword tag verify (order-proof)
        if (!m) {
          #pragma unroll
          for (int i = 0; i < 8; ++i)
            asm volatile("global_load_dwordx4 %0, %1, off sc0"
                         : "=v"(d[i]) : "v"(abase + (size_t)i * 256) : "memory");
        } else {
          #pragma unroll
          for (int i = 0; i < 8; ++i)
            asm volatile("global_load_dwordx4 %0, %1, off sc1"
                         : "=v"(d[i]) : "v"(abase + (size_t)i * 256) : "memory");
        }
        asm volatile("s_waitcnt vmcnt(0)" ::: "memory");
        __builtin_amdgcn_sched_barrier(0);
        u32 bad = 0;
        #pragma unroll
        for (int i = 0; i < 8; ++i) {
          u32x4 q = d[i];
          bad |= (q.x ^ texp) | (q.y ^ texp) | (q.z ^ texp) | (q.w ^ texp);
        }
        bad &= 0x40004000u;
        if (__ballot(bad != 0) == 0ULL) break;
      }
      __builtin_amdgcn_s_sleep(1);
      if (++tries > 512) coh = 1;      // placement-proof escalation
      if (tries > (1 << 17)) break;    // fail loud (absmax) instead of hang
    }

    // --- strip tag bits (bit14 of each f16 is 0 for |h|<=1) + MFMA ---
    f32x4 acc[6];
    #pragma unroll
    for (int c = 0; c < 6; ++c) acc[c] = (f32x4){0.f, 0.f, 0.f, 0.f};
    #pragma unroll
    for (int k8 = 0; k8 < 8; ++k8) {
      u32x4 q = d[k8] & 0xBFFFBFFFu;
      f16x8 a = __builtin_bit_cast(f16x8, q);
      #pragma unroll
      for (int c = 0; c < 6; ++c)
        acc[c] = __builtin_amdgcn_mfma_f32_16x16x32_f16(a, breg[c][k8], acc[c], 0, 0, 0);
    }

    {
      float* q = red[w][lane];
      #pragma unroll
      for (int c = 0; c < 6; ++c)
        #pragma unroll
        for (int r = 0; r < 4; ++r) q[c * 4 + r] = acc[c][r];
    }
    __syncthreads();                                   // S2

    // per-thread reduce over 4 K-quarters + gate epilogue (2 dims)
    {
      int tm = tokL[row * 259 + t];
      int tok = tm & 0xFFFF;
      u16* trc = trH + (t & 15) * 512;
      #pragma unroll
      for (int dh = 0; dh < 2; ++dh) {
        float a0 = 0.f, a1 = 0.f, a2 = 0.f;
        #pragma unroll
        for (int ww = 0; ww < 4; ++ww) {
          const float* q = red[ww][lane_src];
          a0 += q[(0 * 2 + dh) * 4 + rg];
          a1 += q[(1 * 2 + dh) * 4 + rg];
          a2 += q[(2 * 2 + dh) * 4 + rg];
        }
        int dglob = dimb + dh * 16;
        float z  = sigmoidf_(Pl[0][dglob][tok] + a0);
        float r_ = sigmoidf_(Pl[1][dglob][tok] + a1);
        float b1h = dh ? b1h1 : b1h0;
        float hh = tanh_fast(Pl[2][dglob][tok] + r_ * (a2 + b1h));
        float h = dh ? hc1 : hc0;
        if (tm >= 0) h = z * h + (1.0f - z) * hh;
        if (dh) hc1 = h; else hc0 = h;
        trc[(dglob >> 3) * 128 + row * 8 + (dglob & 7)] = f2h_bits(h);
      }
    }
    __syncthreads();                                   // S3

    if (w == 0) {
      // lane sl holds trc u16 idx sl*8+j = h[row=sl&15][kk=(sl>>4)*8+j],
      // exactly the consumer A-fragment order (verified R1).
      u32x4 tr4 = ((const u32x4*)trH)[(t & 15) * 64 + lane];
      u32 tmask = ((u32)((t + 1) & 1) << 14) | ((u32)((t + 1) & 2) << 29);
      u32x4 o = tr4 | tmask;
      u32* eb = exch + (size_t)(gt * 3 + slot_p) * SLOT_U32 + ds * 256 + lane * 4;
      if (!dirty)
        asm volatile("global_store_dwordx4 %0, %1, off"
                     :: "v"(eb), "v"(o) : "memory");     // dirty in shared L2
      else
        asm volatile("global_store_dwordx4 %0, %1, off sc1"
                     :: "v"(eb), "v"(o) : "memory");     // write-through (safe)
      // doorbell: monotonic per-producer counter, plain dword store.
      // Posted after data in program order; landing order irrelevant
      // (tag verify is the truth).
      if (lane == 0) {
        u32* dbp = db + (size_t)(gt * 4 + (ds >> 3)) * 32 + (ds & 7);
        u32 val = (u32)(t + 1);
        if (!dirty)
          asm volatile("global_store_dword %0, %1, off"
                       :: "v"(dbp), "v"(val) : "memory");
        else
          asm volatile("global_store_dword %0, %1, off sc1"
                       :: "v"(dbp), "v"(val) : "memory");
      }
    }

    // --- Hout burst: every 16 steps, coalesced 1KB runs, all waves ---
    if ((t & 15) == 15) {
      int c = tid >> 4, s = tid & 15;
      int T4 = t >> 4;
      int b = gt * 16 + c;
      const u32x4* src = (const u32x4*)trH;
      u32x4* dstv = (u32x4*)Hout;
      size_t dbase = ((size_t)(b * 16 + T4) * 32 + ds) * 64;
      #pragma unroll
      for (int k = 0; k < 4; ++k) {
        int e = s * 4 + k;
        int quad = e >> 4, t15 = e & 15;
        dstv[dbase + e] = src[t15 * 64 + quad * 16 + c];
      }
    }
    slot_c = slot_p;
    slot_p = (slot_p == 2) ? 0 : slot_p + 1;
  }
}

// ---------- dense epilogue (unchanged; Hout layout identical) ----------
__global__ __launch_bounds__(256) void dense_mfma(
    const u16* __restrict__ HoutImg, const uint4* __restrict__ dimg,
    const float* __restrict__ dbf, void* __restrict__ out,
    const int* __restrict__ flag) {
  __shared__ uint4 Bl[48 * 64];
  int tid = threadIdx.x;
  int w = tid >> 6, lane = tid & 63;
  int quad = lane >> 4, vi = lane & 15;
  int gt0 = blockIdx.x * 8 + w * 2;

  f32x4 acc[2][3];
  #pragma unroll
  for (int i = 0; i < 2; ++i)
    #pragma unroll
    for (int c = 0; c < 3; ++c) acc[i][c] = (f32x4){0.f, 0.f, 0.f, 0.f};

  for (int half = 0; half < 2; ++half) {
    for (int i = tid; i < 48 * 64; i += 256) Bl[i] = dimg[half * 48 * 64 + i];
    __syncthreads();
    #pragma unroll
    for (int ks16 = 0; ks16 < 16; ++ks16) {
      int ks = half * 16 + ks16;
      f16x8 a0 = __builtin_bit_cast(
          f16x8, ((const uint4*)HoutImg)[((size_t)gt0 * 32 + ks) * 64 + lane]);
      f16x8 a1 = __builtin_bit_cast(
          f16x8, ((const uint4*)HoutImg)[(((size_t)gt0 + 1) * 32 + ks) * 64 + lane]);
      #pragma unroll
      for (int c = 0; c < 3; ++c) {
        f16x8 bf = __builtin_bit_cast(f16x8, Bl[(ks16 * 3 + c) * 64 + lane]);
        acc[0][c] = __builtin_amdgcn_mfma_f32_16x16x32_f16(a0, bf, acc[0][c], 0, 0, 0);
        acc[1][c] = __builtin_amdgcn_mfma_f32_16x16x32_f16(a1, bf, acc[1][c], 0, 0, 0);
      }
    }
    __syncthreads();
  }

  int isf = *flag;
  #pragma unroll
  for (int i = 0; i < 2; ++i) {
    #pragma unroll
    for (int c = 0; c < 3; ++c) {
      int v = c * 16 + vi;
      if (v >= VOCAB) continue;
      float bias = dbf[v];
      #pragma unroll
      for (int rg = 0; rg < 4; ++rg) {
        size_t bt = (size_t)(gt0 + i) * 16 + quad * 4 + rg;
        float val = acc[i][c][rg] + bias;
        if (isf) ((float*)out)[bt * VOCAB + v] = val;
        else     ((u16*)out)[bt * VOCAB + v] = f2bf(val);
      }
    }
  }
}

// ---------- launch ----------

extern "C" void kernel_launch(void* const* d_in, const int* in_sizes, int n_in,
                              void* d_out, int out_size, void* d_ws, size_t ws_size,
                              hipStream_t stream) {
  const int* x            = (const int*)d_in[0];
  const unsigned char* mk = (const unsigned char*)d_in[1];

  char* ws = (char*)d_ws;
  int*   flag    = (int*)(ws + 0);
  float* dbf     = (float*)(ws + 4 * 1024);
  float* gbf     = (float*)(ws + 8 * 1024);          // 24 KB
  int*   rolectl = (int*)(ws + 32 * 1024);           // 64 B role counters
  u32*   db      = (u32*)(ws + 48 * 1024);           // 4 KB doorbells
  int*   tokm    = (int*)(ws + 64 * 1024);           // 128 KB
  u16*   dimg    = (u16*)(ws + 192 * 1024);          // 96 KB
  float* P       = (float*)(ws + 288 * 1024);        // 504 KB
  float* P2      = (float*)(ws + 800 * 1024);        // 504 KB
  u32*   exch    = (u32*)(ws + 1312 * 1024);         // 768 KB (8 gt x 3 x 32 KB)
  u16*   Wimg    = (u16*)(ws + 3456 * 1024);         // 6 MB
  u16*   Hout    = (u16*)(ws + 10 * 1024 * 1024);    // 64 MB

  detect_kernel<<<1, 256, 0, stream>>>((const u16*)d_in[4], flag);
  conv_kernel<<<(2 * H3 + 255) / 256, 256, 0, stream>>>(d_in[5], gbf, 2 * H3, flag);
  conv_kernel<<<1, 256, 0, stream>>>(d_in[7], dbf, VOCAB, flag);
  tokm_kernel<<<BT / 256, 256, 0, stream>>>(x, mk, tokm);
  proj_kernel<<<VOCAB * (H3 / 256), 256, 0, stream>>>(d_in[2], d_in[3], gbf, P, flag);
  p2_kernel<<<H3, 64, 0, stream>>>(P, gbf, P2);
  pack_wimg_kernel<<<(32 * 32 * 6 * 64 * 8) / 256, 256, 0, stream>>>(d_in[4], Wimg, flag);
  pack_dimg_kernel<<<(32 * 3 * 64 * 8) / 256, 256, 0, stream>>>(d_in[6], dimg, flag);
  // slot 0 zeros = h_0 = 0 with tag 0; slots 1,2 zeros never match tags 1,2.
  hipMemsetAsync(exch, 0, (size_t)8 * NSLOT * SLOT_U32 * 4, stream);
  hipMemsetAsync(rolectl, 0, 64, stream);
  hipMemsetAsync(db, 0, 4 * 1024, stream);

  gru_persist<<<256, 256, 0, stream>>>((const uint4*)Wimg, tokm, P2, gbf,
                                       exch, Hout, rolectl, db);
  dense_mfma<<<256, 256, 0, stream>>>(Hout, (const uint4*)dimg, dbf, d_out, flag);
}